// Round 1
// baseline (135.925 us; speedup 1.0000x reference)
//
#include <hip/hip_runtime.h>
#include <math.h>

#define N 768
#define F 16
#define EMB 32
#define HU 64
#define HE 68
#define GAMMA 0.9f

__device__ __forceinline__ float softplus_f(float x) {
    // numerically stable: max(x,0) + log1p(exp(-|x|))
    return fmaxf(x, 0.f) + log1pf(__expf(-fabsf(x)));
}

// ---------------- Kernel A: h = x@W (global & local) + attention scores ----
__global__ __launch_bounds__(256) void k_proj(
    const float* __restrict__ x,
    const float* __restrict__ Wg, const float* __restrict__ asg, const float* __restrict__ adg,
    const float* __restrict__ Wl, const float* __restrict__ asl, const float* __restrict__ adl,
    float* __restrict__ hg, float* __restrict__ hl,
    float* __restrict__ sgs, float* __restrict__ sgd,
    float* __restrict__ sls, float* __restrict__ sld)
{
    __shared__ float sWg[F * EMB], sWl[F * EMB];
    __shared__ float sasg[EMB], sadg[EMB], sasl[EMB], sadl[EMB];
    int t = threadIdx.x;
    for (int k = t; k < F * EMB; k += 256) { sWg[k] = Wg[k]; sWl[k] = Wl[k]; }
    if (t < EMB) { sasg[t] = asg[t]; sadg[t] = adg[t]; sasl[t] = asl[t]; sadl[t] = adl[t]; }
    __syncthreads();

    int i = blockIdx.x * 256 + t;
    if (i >= N) return;

    float xv[F];
#pragma unroll
    for (int f = 0; f < F; ++f) xv[f] = x[i * F + f];

    float ds_g = 0.f, dd_g = 0.f, ds_l = 0.f, dd_l = 0.f;
#pragma unroll
    for (int e = 0; e < EMB; ++e) {
        float hg_e = 0.f, hl_e = 0.f;
#pragma unroll
        for (int f = 0; f < F; ++f) {
            hg_e += xv[f] * sWg[f * EMB + e];
            hl_e += xv[f] * sWl[f * EMB + e];
        }
        hg[i * EMB + e] = hg_e;
        hl[i * EMB + e] = hl_e;
        ds_g += hg_e * sasg[e];  dd_g += hg_e * sadg[e];
        ds_l += hl_e * sasl[e];  dd_l += hl_e * sadl[e];
    }
    sgs[i] = ds_g; sgd[i] = dd_g; sls[i] = ds_l; sld[i] = dd_l;
}

// ---------------- Kernel B: masked softmax GAT aggregate (block per row) ---
__global__ __launch_bounds__(256) void k_gat(
    const float* __restrict__ adj,
    const float* __restrict__ hg, const float* __restrict__ hl,
    const float* __restrict__ sgs, const float* __restrict__ sgd,
    const float* __restrict__ sls, const float* __restrict__ sld,
    float* __restrict__ yg, float* __restrict__ yl)
{
    int i = blockIdx.x;
    int t = threadIdx.x;
    __shared__ float att[N];
    __shared__ float red[256];
    __shared__ float acc[8 * EMB];
    const float* arow = adj + (size_t)i * N;

    for (int pass = 0; pass < 2; ++pass) {
        const float* ss = pass ? sls : sgs;
        const float* sd = pass ? sld : sgd;
        const float* h  = pass ? hl  : hg;
        float* y        = pass ? yl  : yg;
        float si = ss[i];

        // row max over valid entries (diag always valid)
        float m = -1e30f;
        for (int j = t; j < N; j += 256) {
            if (arow[j] > 0.f) {
                float e = si + sd[j];
                e = (e > 0.f) ? e : 0.2f * e;   // leaky_relu(0.2)
                m = fmaxf(m, e);
            }
        }
        red[t] = m; __syncthreads();
        for (int s = 128; s > 0; s >>= 1) {
            if (t < s) red[t] = fmaxf(red[t], red[t + s]);
            __syncthreads();
        }
        m = red[0]; __syncthreads();

        // p = exp(e - m) on valid entries, row sum
        float lsum = 0.f;
        for (int j = t; j < N; j += 256) {
            float p = 0.f;
            if (arow[j] > 0.f) {
                float e = si + sd[j];
                e = (e > 0.f) ? e : 0.2f * e;
                p = __expf(e - m);
                lsum += p;
            }
            att[j] = p;
        }
        red[t] = lsum; __syncthreads();
        for (int s = 128; s > 0; s >>= 1) {
            if (t < s) red[t] += red[t + s];
            __syncthreads();
        }
        float inv = 1.f / red[0]; __syncthreads();

        // aggregate y[i][d] = inv * sum_j att[j]*h[j][d]
        int d = t & 31, c = t >> 5;        // 8 chunks x 96 columns
        float a = 0.f;
        int j0 = c * 96;
        for (int j = j0; j < j0 + 96; ++j) {
            float p = att[j];
            if (p != 0.f) a += p * h[j * EMB + d];
        }
        acc[c * EMB + d] = a; __syncthreads();
        if (t < EMB) {
            float s2 = 0.f;
#pragma unroll
            for (int c2 = 0; c2 < 8; ++c2) s2 += acc[c2 * EMB + t];
            y[i * EMB + t] = s2 * inv;
        }
        __syncthreads();
    }
}

// ---------------- Kernel C: per-node heads -------------------------------
__global__ __launch_bounds__(256) void k_heads(
    const float* __restrict__ yg, const float* __restrict__ yl,
    const float* __restrict__ uW1, const float* __restrict__ ub1,
    const float* __restrict__ eW1, const float* __restrict__ eb1,
    const float* __restrict__ vW1, const float* __restrict__ vb1,
    const float* __restrict__ vW2, const float* __restrict__ vb2,
    float* __restrict__ urb, float* __restrict__ ucT,
    float* __restrict__ erb, float* __restrict__ ecT,
    float* __restrict__ val)
{
    __shared__ float suW1[2 * EMB * HU];        // 64x64
    __shared__ float seW1[(2 * EMB + 2) * HE];  // 66x68
    __shared__ float svW1[EMB * 64];            // 32x64
    __shared__ float svW2[64];
    int t = threadIdx.x;
    for (int k = t; k < 2 * EMB * HU; k += 256) suW1[k] = uW1[k];
    for (int k = t; k < (2 * EMB + 2) * HE; k += 256) seW1[k] = eW1[k];
    for (int k = t; k < EMB * 64; k += 256) svW1[k] = vW1[k];
    if (t < 64) svW2[t] = vW2[t];
    __syncthreads();

    int i = blockIdx.x * 256 + t;
    if (i >= N) return;

    float g[EMB], l[EMB];
#pragma unroll
    for (int e = 0; e < EMB; ++e) { g[e] = yg[i * EMB + e]; l[e] = yl[i * EMB + e]; }

    // value head
    float acc = 0.f;
    for (int h2 = 0; h2 < 64; ++h2) {
        float v = vb1[h2];
#pragma unroll
        for (int e = 0; e < EMB; ++e) v += g[e] * svW1[e * 64 + h2];
        acc += fmaxf(v, 0.f) * svW2[h2];
    }
    acc += vb2[0];
    val[i] = -softplus_f(acc);

    // util row/col halves (fold ub1 into row half)
    for (int h2 = 0; h2 < HU; ++h2) {
        float r = 0.f, c = 0.f;
#pragma unroll
        for (int e = 0; e < EMB; ++e) {
            r += g[e] * suW1[e * HU + h2];
            c += g[e] * suW1[(e + EMB) * HU + h2];
        }
        urb[i * HU + h2] = r + ub1[h2];
        ucT[h2 * N + i] = c;
    }
    // ext row/col halves (fold eb1 into row half)
    for (int h2 = 0; h2 < HE; ++h2) {
        float r = 0.f, c = 0.f;
#pragma unroll
        for (int e = 0; e < EMB; ++e) {
            r += l[e] * seW1[e * HE + h2];
            c += l[e] * seW1[(e + EMB) * HE + h2];
        }
        erb[i * HE + h2] = r + eb1[h2];
        ecT[h2 * N + i] = c;
    }
}

// ---------------- Kernel D: fused pairwise util/ext/f_val ----------------
__global__ __launch_bounds__(256) void k_final(
    const float* __restrict__ adj, const float* __restrict__ pi,
    const float* __restrict__ urb, const float* __restrict__ ucT,
    const float* __restrict__ erb, const float* __restrict__ ecT,
    const float* __restrict__ val,
    const float* __restrict__ uW2, const float* __restrict__ ub2,
    const float* __restrict__ eW1, const float* __restrict__ eb2,
    const float* __restrict__ eW2,
    float* __restrict__ out)
{
    int i = blockIdx.x;
    int t = threadIdx.x;
    __shared__ float ur_s[HU], er_s[HE], uW2s[HU], eW2s[HE], w0[HE], w1[HE];
    if (t < HU) { ur_s[t] = urb[i * HU + t]; uW2s[t] = uW2[t]; }
    if (t < HE) {
        er_s[t] = erb[i * HE + t];
        eW2s[t] = eW2[t];
        w0[t] = eW1[(2 * EMB) * HE + t];
        w1[t] = eW1[(2 * EMB + 1) * HE + t];
    }
    __syncthreads();

    float vi = val[i];
    float ub2v = ub2[0], eb2v = eb2[0];

    for (int j = t; j < N; j += 256) {
        float a = adj[(size_t)i * N + j];
        float base = GAMMA * val[j] - vi;
        float o0 = base, o1 = base;
        if (a > 0.f) {
            // util
            float accu = 0.f;
            for (int h = 0; h < HU; ++h) {
                float v = ur_s[h] + ucT[h * N + j];
                accu += fmaxf(v, 0.f) * uW2s[h];
            }
            float util = -softplus_f(accu + ub2v);
            // ext for both batches
            size_t p0i = (((size_t)0 * N + i) * N + j) * 2;
            size_t p1i = (((size_t)1 * N + i) * N + j) * 2;
            float p00 = pi[p0i], p01 = pi[p0i + 1];
            float p10 = pi[p1i], p11 = pi[p1i + 1];
            float acc0 = 0.f, acc1 = 0.f;
            for (int h = 0; h < HE; ++h) {
                float com = er_s[h] + ecT[h * N + j];
                float v0 = com + p00 * w0[h] + p01 * w1[h];
                float v1 = com + p10 * w0[h] + p11 * w1[h];
                acc0 += fmaxf(v0, 0.f) * eW2s[h];
                acc1 += fmaxf(v1, 0.f) * eW2s[h];
            }
            float ext0 = -softplus_f(acc0 + eb2v);
            float ext1 = -softplus_f(acc1 + eb2v);
            o0 += (util + ext0) * a;
            o1 += (util + ext1) * a;
        }
        out[((size_t)0 * N + i) * N + j] = o0;
        out[((size_t)1 * N + i) * N + j] = o1;
    }
}

extern "C" void kernel_launch(void* const* d_in, const int* in_sizes, int n_in,
                              void* d_out, int out_size, void* d_ws, size_t ws_size,
                              hipStream_t stream) {
    const float* x   = (const float*)d_in[0];
    const float* pi  = (const float*)d_in[2];
    const float* adj = (const float*)d_in[4];
    const float* Wg  = (const float*)d_in[5];
    const float* asg = (const float*)d_in[6];
    const float* adg = (const float*)d_in[7];
    const float* Wl  = (const float*)d_in[8];
    const float* asl = (const float*)d_in[9];
    const float* adl = (const float*)d_in[10];
    const float* uW1 = (const float*)d_in[11];
    const float* ub1 = (const float*)d_in[12];
    const float* uW2 = (const float*)d_in[13];
    const float* ub2 = (const float*)d_in[14];
    const float* eW1 = (const float*)d_in[15];
    const float* eb1 = (const float*)d_in[16];
    const float* eW2 = (const float*)d_in[17];
    const float* eb2 = (const float*)d_in[18];
    const float* vW1 = (const float*)d_in[19];
    const float* vb1 = (const float*)d_in[20];
    const float* vW2 = (const float*)d_in[21];
    const float* vb2 = (const float*)d_in[22];
    float* out = (float*)d_out;

    float* ws = (float*)d_ws;
    float* hg  = ws;              ws += N * EMB;
    float* hl  = ws;              ws += N * EMB;
    float* sgs = ws;              ws += N;
    float* sgd = ws;              ws += N;
    float* sls = ws;              ws += N;
    float* sld = ws;              ws += N;
    float* yg  = ws;              ws += N * EMB;
    float* yl  = ws;              ws += N * EMB;
    float* valp= ws;              ws += N;
    float* urb = ws;              ws += N * HU;
    float* ucT = ws;              ws += HU * N;
    float* erb = ws;              ws += N * HE;
    float* ecT = ws;              ws += HE * N;

    k_proj<<<(N + 255) / 256, 256, 0, stream>>>(x, Wg, asg, adg, Wl, asl, adl,
                                                hg, hl, sgs, sgd, sls, sld);
    k_gat<<<N, 256, 0, stream>>>(adj, hg, hl, sgs, sgd, sls, sld, yg, yl);
    k_heads<<<(N + 255) / 256, 256, 0, stream>>>(yg, yl, uW1, ub1, eW1, eb1,
                                                 vW1, vb1, vW2, vb2,
                                                 urb, ucT, erb, ecT, valp);
    k_final<<<N, 256, 0, stream>>>(adj, pi, urb, ucT, erb, ecT, valp,
                                   uW2, ub2, eW1, eb2, eW2, out);
}

// Round 2
// 62.233 us; speedup vs baseline: 2.1841x; 2.1841x over previous
//
#include <hip/hip_runtime.h>
#include <math.h>

#define N 768
#define F 16
#define EMB 32
#define HU 64
#define HE 68
#define GAMMA 0.9f

__device__ __forceinline__ float softplus_f(float x) {
    return fmaxf(x, 0.f) + log1pf(__expf(-fabsf(x)));
}

// ---------------- Kernel A: h = x@W (global & local) + attention scores ----
// 32 lanes per node (lane = emb index e), 8 nodes per 256-thread block.
__global__ __launch_bounds__(256) void k_proj(
    const float* __restrict__ x,
    const float* __restrict__ Wg, const float* __restrict__ asg, const float* __restrict__ adg,
    const float* __restrict__ Wl, const float* __restrict__ asl, const float* __restrict__ adl,
    float* __restrict__ hg, float* __restrict__ hl,
    float* __restrict__ sgs, float* __restrict__ sgd,
    float* __restrict__ sls, float* __restrict__ sld)
{
    int t = threadIdx.x;
    int i = blockIdx.x * 8 + (t >> 5);
    int e = t & 31;

    float xv[F];
#pragma unroll
    for (int f = 0; f < F; ++f) xv[f] = x[i * F + f];   // broadcast within group

    float hg_e = 0.f, hl_e = 0.f;
#pragma unroll
    for (int f = 0; f < F; ++f) {
        hg_e += xv[f] * Wg[f * EMB + e];
        hl_e += xv[f] * Wl[f * EMB + e];
    }
    hg[i * EMB + e] = hg_e;
    hl[i * EMB + e] = hl_e;

    float ds_g = hg_e * asg[e];
    float dd_g = hg_e * adg[e];
    float ds_l = hl_e * asl[e];
    float dd_l = hl_e * adl[e];
#pragma unroll
    for (int off = 16; off >= 1; off >>= 1) {    // stays within 32-lane half
        ds_g += __shfl_xor(ds_g, off);
        dd_g += __shfl_xor(dd_g, off);
        ds_l += __shfl_xor(ds_l, off);
        dd_l += __shfl_xor(dd_l, off);
    }
    if (e == 0) { sgs[i] = ds_g; sgd[i] = dd_g; sls[i] = ds_l; sld[i] = dd_l; }
}

// ---------------- Kernel B: masked softmax GAT aggregate (block per row) ---
__global__ __launch_bounds__(256) void k_gat(
    const float* __restrict__ adj,
    const float* __restrict__ hg, const float* __restrict__ hl,
    const float* __restrict__ sgs, const float* __restrict__ sgd,
    const float* __restrict__ sls, const float* __restrict__ sld,
    float* __restrict__ yg, float* __restrict__ yl)
{
    int i = blockIdx.x;
    int t = threadIdx.x;
    int lane = t & 63, wid = t >> 6;
    __shared__ float attg[N], attl[N];
    __shared__ float redA[4], redB[4], redC[4], redD[4];
    __shared__ float accg[8 * EMB], accl[8 * EMB];
    const float* arow = adj + (size_t)i * N;

    float si_g = sgs[i], si_l = sls[i];

    // phase 1: masked leaky-relu scores + row max (both GATs, adj read ONCE)
    float mg = -1e30f, ml = -1e30f;
    for (int j = t; j < N; j += 256) {
        float a = arow[j];
        float eg = -1e30f, el = -1e30f;
        if (a > 0.f) {
            eg = si_g + sgd[j]; eg = (eg > 0.f) ? eg : 0.2f * eg;
            el = si_l + sld[j]; el = (el > 0.f) ? el : 0.2f * el;
            mg = fmaxf(mg, eg); ml = fmaxf(ml, el);
        }
        attg[j] = eg; attl[j] = el;
    }
#pragma unroll
    for (int off = 32; off >= 1; off >>= 1) {
        mg = fmaxf(mg, __shfl_xor(mg, off));
        ml = fmaxf(ml, __shfl_xor(ml, off));
    }
    if (lane == 0) { redA[wid] = mg; redB[wid] = ml; }
    __syncthreads();
    mg = fmaxf(fmaxf(redA[0], redA[1]), fmaxf(redA[2], redA[3]));
    ml = fmaxf(fmaxf(redB[0], redB[1]), fmaxf(redB[2], redB[3]));

    // phase 2: exp + sums
    float sumg = 0.f, suml = 0.f;
    for (int j = t; j < N; j += 256) {
        float eg = attg[j], el = attl[j];
        float pg = (eg > -1e29f) ? __expf(eg - mg) : 0.f;
        float pl = (el > -1e29f) ? __expf(el - ml) : 0.f;
        attg[j] = pg; attl[j] = pl;
        sumg += pg; suml += pl;
    }
#pragma unroll
    for (int off = 32; off >= 1; off >>= 1) {
        sumg += __shfl_xor(sumg, off);
        suml += __shfl_xor(suml, off);
    }
    if (lane == 0) { redC[wid] = sumg; redD[wid] = suml; }
    __syncthreads();
    float invg = 1.f / (redC[0] + redC[1] + redC[2] + redC[3]);
    float invl = 1.f / (redD[0] + redD[1] + redD[2] + redD[3]);

    // phase 3: aggregate y[i][d] = inv * sum_j att[j]*h[j][d], 8 chunks x 96
    int d = t & 31, c = t >> 5;
    float ag = 0.f, al = 0.f;
    int j0 = c * 96;
    for (int j = j0; j < j0 + 96; ++j) {
        float pg = attg[j];
        if (pg != 0.f) ag += pg * hg[j * EMB + d];
        float pl = attl[j];
        if (pl != 0.f) al += pl * hl[j * EMB + d];
    }
    accg[c * EMB + d] = ag; accl[c * EMB + d] = al;
    __syncthreads();
    if (t < EMB) {
        float s2 = 0.f;
#pragma unroll
        for (int c2 = 0; c2 < 8; ++c2) s2 += accg[c2 * EMB + t];
        yg[i * EMB + t] = s2 * invg;
    } else if (t < 2 * EMB) {
        int d2 = t - EMB;
        float s2 = 0.f;
#pragma unroll
        for (int c2 = 0; c2 < 8; ++c2) s2 += accl[c2 * EMB + d2];
        yl[i * EMB + d2] = s2 * invl;
    }
}

// ---------------- Kernel C: per-node heads, one 64-lane wave per node -----
// lane h = hidden unit; 4 nodes per 256-thread block -> 192 blocks.
__global__ __launch_bounds__(256) void k_heads(
    const float* __restrict__ yg, const float* __restrict__ yl,
    const float* __restrict__ uW1, const float* __restrict__ ub1,
    const float* __restrict__ eW1, const float* __restrict__ eb1,
    const float* __restrict__ vW1, const float* __restrict__ vb1,
    const float* __restrict__ vW2, const float* __restrict__ vb2,
    float* __restrict__ urb, float* __restrict__ ucR,
    float* __restrict__ erb, float* __restrict__ ecR,
    float* __restrict__ val)
{
    int t = threadIdx.x;
    int i = blockIdx.x * 4 + (t >> 6);
    int h = t & 63;

    float g[EMB], l[EMB];
#pragma unroll
    for (int e = 0; e < EMB; ++e) { g[e] = yg[i * EMB + e]; l[e] = yl[i * EMB + e]; }

    // value head: lane h computes hidden unit h, wave-reduce
    float v = vb1[h];
#pragma unroll
    for (int e = 0; e < EMB; ++e) v += g[e] * vW1[e * 64 + h];
    float rv = fmaxf(v, 0.f) * vW2[h];
#pragma unroll
    for (int off = 32; off >= 1; off >>= 1) rv += __shfl_xor(rv, off);
    if (h == 0) val[i] = -softplus_f(rv + vb2[0]);

    // util row/col halves (bias folded into row half)
    float r = ub1[h], c = 0.f;
#pragma unroll
    for (int e = 0; e < EMB; ++e) {
        r += g[e] * uW1[e * HU + h];
        c += g[e] * uW1[(e + EMB) * HU + h];
    }
    urb[i * HU + h] = r;
    ucR[i * HU + h] = c;

    // ext row/col halves
    float er = eb1[h], ec = 0.f;
#pragma unroll
    for (int e = 0; e < EMB; ++e) {
        er += l[e] * eW1[e * HE + h];
        ec += l[e] * eW1[(e + EMB) * HE + h];
    }
    erb[i * HE + h] = er;
    ecR[i * HE + h] = ec;
    if (h < HE - 64) {               // remaining 4 hidden units (64..67)
        int h2 = 64 + h;
        float er2 = eb1[h2], ec2 = 0.f;
#pragma unroll
        for (int e = 0; e < EMB; ++e) {
            er2 += l[e] * eW1[e * HE + h2];
            ec2 += l[e] * eW1[(e + EMB) * HE + h2];
        }
        erb[i * HE + h2] = er2;
        ecR[i * HE + h2] = ec2;
    }
}

// ---------------- Kernel D: fused pairwise util/ext/f_val ----------------
__global__ __launch_bounds__(256) void k_final(
    const float* __restrict__ adj, const float* __restrict__ pi,
    const float* __restrict__ urb, const float* __restrict__ ucR,
    const float* __restrict__ erb, const float* __restrict__ ecR,
    const float* __restrict__ val,
    const float* __restrict__ uW2, const float* __restrict__ ub2,
    const float* __restrict__ eW1, const float* __restrict__ eb2,
    const float* __restrict__ eW2,
    float* __restrict__ out)
{
    int i = blockIdx.x;
    int t = threadIdx.x;
    __shared__ float ur_s[HU], er_s[HE], uW2s[HU], eW2s[HE], w0[HE], w1[HE];
    if (t < HU) { ur_s[t] = urb[i * HU + t]; uW2s[t] = uW2[t]; }
    if (t < HE) {
        er_s[t] = erb[i * HE + t];
        eW2s[t] = eW2[t];
        w0[t] = eW1[(2 * EMB) * HE + t];
        w1[t] = eW1[(2 * EMB + 1) * HE + t];
    }
    __syncthreads();

    float vi = val[i];
    float ub2v = ub2[0], eb2v = eb2[0];

    for (int j = t; j < N; j += 256) {
        float a = adj[(size_t)i * N + j];
        float base = GAMMA * val[j] - vi;
        float o0 = base, o1 = base;
        if (a > 0.f) {
            // util: 16 float4 steps
            const float4* uc4 = (const float4*)(ucR + (size_t)j * HU);
            float accu = 0.f;
#pragma unroll 4
            for (int h4 = 0; h4 < HU / 4; ++h4) {
                float4 u = uc4[h4];
                int h = h4 * 4;
                accu += fmaxf(ur_s[h + 0] + u.x, 0.f) * uW2s[h + 0];
                accu += fmaxf(ur_s[h + 1] + u.y, 0.f) * uW2s[h + 1];
                accu += fmaxf(ur_s[h + 2] + u.z, 0.f) * uW2s[h + 2];
                accu += fmaxf(ur_s[h + 3] + u.w, 0.f) * uW2s[h + 3];
            }
            float util = -softplus_f(accu + ub2v);
            // ext for both batches
            size_t p0i = (((size_t)0 * N + i) * N + j) * 2;
            size_t p1i = (((size_t)1 * N + i) * N + j) * 2;
            float p00 = pi[p0i], p01 = pi[p0i + 1];
            float p10 = pi[p1i], p11 = pi[p1i + 1];
            const float4* ec4 = (const float4*)(ecR + (size_t)j * HE);
            float acc0 = 0.f, acc1 = 0.f;
#pragma unroll 4
            for (int h4 = 0; h4 < HE / 4; ++h4) {
                float4 ecv = ec4[h4];
                int h = h4 * 4;
#pragma unroll
                for (int q = 0; q < 4; ++q) {
                    float e_c = (q == 0) ? ecv.x : (q == 1) ? ecv.y : (q == 2) ? ecv.z : ecv.w;
                    float com = er_s[h + q] + e_c;
                    acc0 += fmaxf(com + p00 * w0[h + q] + p01 * w1[h + q], 0.f) * eW2s[h + q];
                    acc1 += fmaxf(com + p10 * w0[h + q] + p11 * w1[h + q], 0.f) * eW2s[h + q];
                }
            }
            float ext0 = -softplus_f(acc0 + eb2v);
            float ext1 = -softplus_f(acc1 + eb2v);
            o0 += (util + ext0) * a;
            o1 += (util + ext1) * a;
        }
        out[((size_t)0 * N + i) * N + j] = o0;
        out[((size_t)1 * N + i) * N + j] = o1;
    }
}

extern "C" void kernel_launch(void* const* d_in, const int* in_sizes, int n_in,
                              void* d_out, int out_size, void* d_ws, size_t ws_size,
                              hipStream_t stream) {
    const float* x   = (const float*)d_in[0];
    const float* pi  = (const float*)d_in[2];
    const float* adj = (const float*)d_in[4];
    const float* Wg  = (const float*)d_in[5];
    const float* asg = (const float*)d_in[6];
    const float* adg = (const float*)d_in[7];
    const float* Wl  = (const float*)d_in[8];
    const float* asl = (const float*)d_in[9];
    const float* adl = (const float*)d_in[10];
    const float* uW1 = (const float*)d_in[11];
    const float* ub1 = (const float*)d_in[12];
    const float* uW2 = (const float*)d_in[13];
    const float* ub2 = (const float*)d_in[14];
    const float* eW1 = (const float*)d_in[15];
    const float* eb1 = (const float*)d_in[16];
    const float* eW2 = (const float*)d_in[17];
    const float* eb2 = (const float*)d_in[18];
    const float* vW1 = (const float*)d_in[19];
    const float* vb1 = (const float*)d_in[20];
    const float* vW2 = (const float*)d_in[21];
    const float* vb2 = (const float*)d_in[22];
    float* out = (float*)d_out;

    float* ws = (float*)d_ws;
    float* hg  = ws;              ws += N * EMB;
    float* hl  = ws;              ws += N * EMB;
    float* sgs = ws;              ws += N;
    float* sgd = ws;              ws += N;
    float* sls = ws;              ws += N;
    float* sld = ws;              ws += N;
    float* yg  = ws;              ws += N * EMB;
    float* yl  = ws;              ws += N * EMB;
    float* valp= ws;              ws += N;
    float* urb = ws;              ws += N * HU;
    float* ucR = ws;              ws += N * HU;
    float* erb = ws;              ws += N * HE;
    float* ecR = ws;              ws += N * HE;

    k_proj<<<N / 8, 256, 0, stream>>>(x, Wg, asg, adg, Wl, asl, adl,
                                      hg, hl, sgs, sgd, sls, sld);
    k_gat<<<N, 256, 0, stream>>>(adj, hg, hl, sgs, sgd, sls, sld, yg, yl);
    k_heads<<<N / 4, 256, 0, stream>>>(yg, yl, uW1, ub1, eW1, eb1,
                                       vW1, vb1, vW2, vb2,
                                       urb, ucR, erb, ecR, valp);
    k_final<<<N, 256, 0, stream>>>(adj, pi, urb, ucR, erb, ecR, valp,
                                   uW2, ub2, eW1, eb2, eW2, out);
}

// Round 3
// 38.775 us; speedup vs baseline: 3.5055x; 1.6050x over previous
//
#include <hip/hip_runtime.h>
#include <math.h>

#define NN 768
#define FD 16
#define EMB 32
#define HU 64
#define HE 68
#define GAMMA 0.9f

__device__ __forceinline__ float softplus_f(float x) {
    return fmaxf(x, 0.f) + log1pf(__expf(-fabsf(x)));
}

// ---------- Kernel 1: fused GAT (global+local) + per-node heads -----------
// One block per node i. Recomputes h[j]=x[j]@W on the fly for its ~24
// neighbors (cheaper than a cross-kernel round trip). Deterministic
// neighbor compaction (ballot+prefix, ordered by j).
__global__ __launch_bounds__(256) void k_gatheads(
    const float* __restrict__ x, const float* __restrict__ adj,
    const float* __restrict__ Wg, const float* __restrict__ asg, const float* __restrict__ adg,
    const float* __restrict__ Wl, const float* __restrict__ asl, const float* __restrict__ adl,
    const float* __restrict__ uW1, const float* __restrict__ ub1,
    const float* __restrict__ eW1, const float* __restrict__ eb1,
    const float* __restrict__ vW1, const float* __restrict__ vb1,
    const float* __restrict__ vW2, const float* __restrict__ vb2,
    float* __restrict__ urb, float* __restrict__ ucR,
    float* __restrict__ erb, float* __restrict__ ecR,
    float* __restrict__ val, int* __restrict__ nbrg, int* __restrict__ cntg)
{
    int i = blockIdx.x;
    int t = threadIdx.x;
    int lane = t & 63, wid = t >> 6;
    int gid = t >> 5, l32 = t & 31;

    __shared__ float sWg[FD * EMB], sWl[FD * EMB];
    __shared__ float sadg[EMB], sadl[EMB], sasg[EMB], sasl[EMB];
    __shared__ int   s_nbr[NN];
    __shared__ float s_scg[NN], s_scl[NN];
    __shared__ int   s_wcnt[4];
    __shared__ int   s_base;
    __shared__ float s_si[2], s_inv[2];
    __shared__ float s_acc[2][8 * EMB];
    __shared__ float s_y[2][EMB];

    for (int k = t; k < FD * EMB; k += 256) { sWg[k] = Wg[k]; sWl[k] = Wl[k]; }
    if (t < EMB) { sadg[t] = adg[t]; sadl[t] = adl[t]; sasg[t] = asg[t]; sasl[t] = asl[t]; }
    if (t == 0) s_base = 0;
    __syncthreads();

    const float* arow = adj + (size_t)i * NN;

    // deterministic stream compaction of neighbor indices (sorted by j)
    for (int c = 0; c < NN / 256; ++c) {
        int j = c * 256 + t;
        bool act = arow[j] > 0.f;
        unsigned long long mask = __ballot(act);
        int within = __popcll(mask & ((1ULL << lane) - 1ULL));
        if (lane == 0) s_wcnt[wid] = __popcll(mask);
        __syncthreads();
        int woff = s_base;
        for (int w = 0; w < wid; ++w) woff += s_wcnt[w];
        if (act) s_nbr[woff + within] = j;
        __syncthreads();
        if (t == 0) s_base += s_wcnt[0] + s_wcnt[1] + s_wcnt[2] + s_wcnt[3];
        __syncthreads();
    }
    int M = s_base;

    // own-node source dots: si = (x_i @ W) . a_src   (gid 0 = global, 1 = local)
    if (gid < 2) {
        const float* W  = gid ? sWl  : sWg;
        const float* av = gid ? sasl : sasg;
        float he = 0.f;
#pragma unroll
        for (int f = 0; f < FD; ++f) he += x[i * FD + f] * W[f * EMB + l32];
        float d = he * av[l32];
#pragma unroll
        for (int off = 16; off >= 1; off >>= 1) d += __shfl_xor(d, off);
        if (l32 == 0) s_si[gid] = d;
    }
    __syncthreads();

    // pass A: leaky-relu scores for all neighbors (8 groups x 32 lanes)
    for (int c0 = 0; c0 < M; c0 += 8) {
        int idx = c0 + gid;
        if (idx < M) {
            int jn = s_nbr[idx];
            float hge = 0.f, hle = 0.f;
#pragma unroll
            for (int f = 0; f < FD; ++f) {
                float xf = x[jn * FD + f];
                hge += xf * sWg[f * EMB + l32];
                hle += xf * sWl[f * EMB + l32];
            }
            float dg = hge * sadg[l32], dl = hle * sadl[l32];
#pragma unroll
            for (int off = 16; off >= 1; off >>= 1) {
                dg += __shfl_xor(dg, off);
                dl += __shfl_xor(dl, off);
            }
            if (l32 == 0) {
                float eg = s_si[0] + dg; eg = (eg > 0.f) ? eg : 0.2f * eg;
                float el = s_si[1] + dl; el = (el > 0.f) ? el : 0.2f * el;
                s_scg[idx] = eg; s_scl[idx] = el;
            }
        }
    }
    __syncthreads();

    // softmax over the M scores (wave 0 only; fixed order -> deterministic)
    if (wid == 0) {
        float mg = -1e30f, ml = -1e30f;
        for (int idx = lane; idx < M; idx += 64) {
            mg = fmaxf(mg, s_scg[idx]); ml = fmaxf(ml, s_scl[idx]);
        }
#pragma unroll
        for (int off = 32; off >= 1; off >>= 1) {
            mg = fmaxf(mg, __shfl_xor(mg, off));
            ml = fmaxf(ml, __shfl_xor(ml, off));
        }
        float sg = 0.f, sl = 0.f;
        for (int idx = lane; idx < M; idx += 64) {
            float pg = __expf(s_scg[idx] - mg); s_scg[idx] = pg; sg += pg;
            float pl = __expf(s_scl[idx] - ml); s_scl[idx] = pl; sl += pl;
        }
#pragma unroll
        for (int off = 32; off >= 1; off >>= 1) {
            sg += __shfl_xor(sg, off);
            sl += __shfl_xor(sl, off);
        }
        if (lane == 0) { s_inv[0] = 1.f / sg; s_inv[1] = 1.f / sl; }
    }
    __syncthreads();

    // pass B: aggregate y = sum_j p_j * h_j (h recomputed; L1-resident x/W)
    float ag = 0.f, al = 0.f;
    for (int c0 = 0; c0 < M; c0 += 8) {
        int idx = c0 + gid;
        if (idx < M) {
            int jn = s_nbr[idx];
            float hge = 0.f, hle = 0.f;
#pragma unroll
            for (int f = 0; f < FD; ++f) {
                float xf = x[jn * FD + f];
                hge += xf * sWg[f * EMB + l32];
                hle += xf * sWl[f * EMB + l32];
            }
            ag += s_scg[idx] * hge;
            al += s_scl[idx] * hle;
        }
    }
    s_acc[0][gid * EMB + l32] = ag;
    s_acc[1][gid * EMB + l32] = al;
    __syncthreads();
    if (t < 2 * EMB) {
        int which = t >> 5, e = t & 31;
        float s = 0.f;
#pragma unroll
        for (int g = 0; g < 8; ++g) s += s_acc[which][g * EMB + e];
        s_y[which][e] = s * s_inv[which];
    }
    __syncthreads();

    // heads: t<64 util unit, t in [64,132) ext unit, wave 3 = val units
    if (t < HU) {
        float r = ub1[t], cc = 0.f;
#pragma unroll
        for (int e = 0; e < EMB; ++e) {
            float y = s_y[0][e];
            r  += y * uW1[e * HU + t];
            cc += y * uW1[(e + EMB) * HU + t];
        }
        urb[i * HU + t] = r;
        ucR[i * HU + t] = cc;
    } else if (t < HU + HE) {
        int u = t - HU;
        float r = eb1[u], cc = 0.f;
#pragma unroll
        for (int e = 0; e < EMB; ++e) {
            float y = s_y[1][e];
            r  += y * eW1[e * HE + u];
            cc += y * eW1[(e + EMB) * HE + u];
        }
        erb[i * HE + u] = r;
        ecR[i * HE + u] = cc;
    } else if (t >= 192) {
        int u = t - 192;                     // wave 3, lane u
        float v = vb1[u];
#pragma unroll
        for (int e = 0; e < EMB; ++e) v += s_y[0][e] * vW1[e * 64 + u];
        float rv = fmaxf(v, 0.f) * vW2[u];
#pragma unroll
        for (int off = 32; off >= 1; off >>= 1) rv += __shfl_xor(rv, off);
        if (u == 0) val[i] = -softplus_f(rv + vb2[0]);
    }

    for (int idx = t; idx < M; idx += 256) nbrg[(size_t)i * NN + idx] = s_nbr[idx];
    if (t == 0) cntg[i] = M;
}

// ---------- Kernel 2: dense base write + sparse edge util/ext -------------
__global__ __launch_bounds__(256) void k_final(
    const float* __restrict__ pi,
    const float* __restrict__ urb, const float* __restrict__ ucR,
    const float* __restrict__ erb, const float* __restrict__ ecR,
    const float* __restrict__ val,
    const float* __restrict__ uW2, const float* __restrict__ ub2,
    const float* __restrict__ eW1, const float* __restrict__ eb2,
    const float* __restrict__ eW2,
    const int* __restrict__ nbrg, const int* __restrict__ cntg,
    float* __restrict__ out)
{
    int i = blockIdx.x;
    int t = threadIdx.x;
    __shared__ float ur_s[HU], uW2s[HU], er_s[HE], eW2s[HE], w0[HE], w1[HE];
    if (t < HU) { ur_s[t] = urb[i * HU + t]; uW2s[t] = uW2[t]; }
    if (t < HE) {
        er_s[t] = erb[i * HE + t];
        eW2s[t] = eW2[t];
        w0[t] = eW1[(2 * EMB) * HE + t];
        w1[t] = eW1[(2 * EMB + 1) * HE + t];
    }
    __syncthreads();

    float vi = val[i];

    // dense base: out[b][i][j] = GAMMA*val[j] - vi  (float4, both batches)
    if (t < NN / 4) {
        float4 vv = ((const float4*)val)[t];
        float4 b;
        b.x = GAMMA * vv.x - vi;
        b.y = GAMMA * vv.y - vi;
        b.z = GAMMA * vv.z - vi;
        b.w = GAMMA * vv.w - vi;
        ((float4*)(out + (size_t)i * NN))[t] = b;
        ((float4*)(out + (size_t)(NN + i) * NN))[t] = b;
    }
    __syncthreads();

    int M = cntg[i];
    float ub2v = ub2[0], eb2v = eb2[0];

    for (int idx = t; idx < M; idx += 256) {
        int jn = nbrg[(size_t)i * NN + idx];
        // util (adj value is exactly 1.0 at edges)
        const float4* uc4 = (const float4*)(ucR + (size_t)jn * HU);
        float accu = 0.f;
#pragma unroll
        for (int h4 = 0; h4 < HU / 4; ++h4) {
            float4 u = uc4[h4]; int h = h4 * 4;
            accu += fmaxf(ur_s[h + 0] + u.x, 0.f) * uW2s[h + 0];
            accu += fmaxf(ur_s[h + 1] + u.y, 0.f) * uW2s[h + 1];
            accu += fmaxf(ur_s[h + 2] + u.z, 0.f) * uW2s[h + 2];
            accu += fmaxf(ur_s[h + 3] + u.w, 0.f) * uW2s[h + 3];
        }
        float util = -softplus_f(accu + ub2v);
        // ext, both batches
        float2 p0 = *(const float2*)(pi + ((size_t)i * NN + jn) * 2);
        float2 p1 = *(const float2*)(pi + ((size_t)(NN + i) * NN + jn) * 2);
        const float4* ec4 = (const float4*)(ecR + (size_t)jn * HE);
        float a0 = 0.f, a1 = 0.f;
#pragma unroll
        for (int h4 = 0; h4 < HE / 4; ++h4) {
            float4 ecv = ec4[h4]; int h = h4 * 4;
            float c0 = er_s[h + 0] + ecv.x;
            float c1 = er_s[h + 1] + ecv.y;
            float c2 = er_s[h + 2] + ecv.z;
            float c3 = er_s[h + 3] + ecv.w;
            a0 += fmaxf(c0 + p0.x * w0[h + 0] + p0.y * w1[h + 0], 0.f) * eW2s[h + 0];
            a1 += fmaxf(c0 + p1.x * w0[h + 0] + p1.y * w1[h + 0], 0.f) * eW2s[h + 0];
            a0 += fmaxf(c1 + p0.x * w0[h + 1] + p0.y * w1[h + 1], 0.f) * eW2s[h + 1];
            a1 += fmaxf(c1 + p1.x * w0[h + 1] + p1.y * w1[h + 1], 0.f) * eW2s[h + 1];
            a0 += fmaxf(c2 + p0.x * w0[h + 2] + p0.y * w1[h + 2], 0.f) * eW2s[h + 2];
            a1 += fmaxf(c2 + p1.x * w0[h + 2] + p1.y * w1[h + 2], 0.f) * eW2s[h + 2];
            a0 += fmaxf(c3 + p0.x * w0[h + 3] + p0.y * w1[h + 3], 0.f) * eW2s[h + 3];
            a1 += fmaxf(c3 + p1.x * w0[h + 3] + p1.y * w1[h + 3], 0.f) * eW2s[h + 3];
        }
        float ext0 = -softplus_f(a0 + eb2v);
        float ext1 = -softplus_f(a1 + eb2v);
        float basej = GAMMA * val[jn] - vi;
        out[(size_t)i * NN + jn]        = basej + util + ext0;
        out[(size_t)(NN + i) * NN + jn] = basej + util + ext1;
    }
}

extern "C" void kernel_launch(void* const* d_in, const int* in_sizes, int n_in,
                              void* d_out, int out_size, void* d_ws, size_t ws_size,
                              hipStream_t stream) {
    const float* x   = (const float*)d_in[0];
    const float* pi  = (const float*)d_in[2];
    const float* adj = (const float*)d_in[4];
    const float* Wg  = (const float*)d_in[5];
    const float* asg = (const float*)d_in[6];
    const float* adg = (const float*)d_in[7];
    const float* Wl  = (const float*)d_in[8];
    const float* asl = (const float*)d_in[9];
    const float* adl = (const float*)d_in[10];
    const float* uW1 = (const float*)d_in[11];
    const float* ub1 = (const float*)d_in[12];
    const float* uW2 = (const float*)d_in[13];
    const float* ub2 = (const float*)d_in[14];
    const float* eW1 = (const float*)d_in[15];
    const float* eb1 = (const float*)d_in[16];
    const float* eW2 = (const float*)d_in[17];
    const float* eb2 = (const float*)d_in[18];
    const float* vW1 = (const float*)d_in[19];
    const float* vb1 = (const float*)d_in[20];
    const float* vW2 = (const float*)d_in[21];
    const float* vb2 = (const float*)d_in[22];
    float* out = (float*)d_out;

    float* ws = (float*)d_ws;
    float* valp = ws;  ws += NN;            // offsets keep 16B alignment:
    float* urb  = ws;  ws += NN * HU;       // 768*65*4  % 16 == 0
    float* ucR  = ws;  ws += NN * HU;
    float* erb  = ws;  ws += NN * HE;       // 768*197*4 % 16 == 0
    float* ecR  = ws;  ws += NN * HE;
    int*   nbrg = (int*)ws;
    int*   cntg = nbrg + (size_t)NN * NN;

    k_gatheads<<<NN, 256, 0, stream>>>(x, adj, Wg, asg, adg, Wl, asl, adl,
                                       uW1, ub1, eW1, eb1, vW1, vb1, vW2, vb2,
                                       urb, ucR, erb, ecR, valp, nbrg, cntg);
    k_final<<<NN, 256, 0, stream>>>(pi, urb, ucR, erb, ecR, valp,
                                    uW2, ub2, eW1, eb2, eW2, nbrg, cntg, out);
}